// Round 1
// baseline (89.602 us; speedup 1.0000x reference)
//
#include <hip/hip_runtime.h>

// SimpleJoinModel: equi-join on integer-valued fp32 key columns.
// left: (N_LEFT, 256) f32, right: (N_RIGHT, 256) f32.
// Keys left[:,left_on] and right[:,right_on] are permutations of 0..N-1
// (exact fp32 integers), so an inverse-permutation table in d_ws gives O(1)
// lookup. Output row i = [left[table[key(right_i)]], right_i]  (512 f32).

#define DCOLS 256   // feature dim of each input
#define OCOLS 512   // output row width

__global__ void build_table_kernel(const float* __restrict__ left,
                                   const int* __restrict__ left_on_p,
                                   int* __restrict__ table,
                                   int n_left) {
    int j = blockIdx.x * blockDim.x + threadIdx.x;
    if (j >= n_left) return;
    int key = (int)left[(size_t)j * DCOLS + left_on_p[0]];
    if (key >= 0 && key < n_left) table[key] = j;
}

// One wave (64 lanes) per output row. Each lane moves one float4 per half:
// 64 lanes * 16 B = 1024 B = one 256-float half-row per vector instruction.
__global__ void join_kernel(const float* __restrict__ left,
                            const float* __restrict__ right,
                            const int* __restrict__ right_on_p,
                            const int* __restrict__ table,
                            float* __restrict__ out,
                            int n_right) {
    int gtid = blockIdx.x * blockDim.x + threadIdx.x;
    int row  = gtid >> 6;          // wave index == output row
    int lane = threadIdx.x & 63;
    if (row >= n_right) return;

    // Same-address load across the wave -> broadcast, effectively free.
    int key = (int)right[(size_t)row * DCOLS + right_on_p[0]];
    int j   = table[key];

    const float4* lsrc = (const float4*)(left  + (size_t)j   * DCOLS);
    const float4* rsrc = (const float4*)(right + (size_t)row * DCOLS);
    float4*       o    = (float4*)(out + (size_t)row * OCOLS);

    o[lane]      = lsrc[lane];   // cols   0..255 : gathered left row
    o[lane + 64] = rsrc[lane];   // cols 256..511 : aligned right row
}

extern "C" void kernel_launch(void* const* d_in, const int* in_sizes, int n_in,
                              void* d_out, int out_size, void* d_ws, size_t ws_size,
                              hipStream_t stream) {
    const float* left     = (const float*)d_in[0];
    const float* right    = (const float*)d_in[1];
    const int*   left_on  = (const int*)d_in[2];   // 1-element scalar array
    const int*   right_on = (const int*)d_in[3];   // 1-element scalar array
    float*       out      = (float*)d_out;

    int n_left  = in_sizes[0] / DCOLS;
    int n_right = in_sizes[1] / DCOLS;

    int* table = (int*)d_ws;   // n_left ints; fully overwritten each call

    {
        int block = 256;
        int grid  = (n_left + block - 1) / block;
        build_table_kernel<<<grid, block, 0, stream>>>(left, left_on, table, n_left);
    }
    {
        int block = 256;                       // 4 waves -> 4 rows per block
        int rows_per_block = block / 64;
        int grid = (n_right + rows_per_block - 1) / rows_per_block;
        join_kernel<<<grid, block, 0, stream>>>(right /*dummy order fix below*/ == nullptr ? nullptr : left,
                                                right, right_on, table, out, n_right);
    }
}